// Round 12
// baseline (11228.274 us; speedup 1.0000x reference)
//
#include <hip/hip_runtime.h>
#include <math.h>

#define Bc 16
#define Tc 2048
#define Dc 512
#define Hc 1024
#define Rc 16

// ---------------------------------------------------------------------------
// Fused projection GEMM: xw = X@Wx and v = X@Wv in one dispatch.
// ---------------------------------------------------------------------------
__global__ __launch_bounds__(256) void gemm_fused(const float* __restrict__ X,
                                                  const float* __restrict__ Wx,
                                                  const float* __restrict__ Wv,
                                                  float* __restrict__ out0,
                                                  float* __restrict__ vout)
{
    __shared__ float As[16][128];
    __shared__ float Bs[16][128];
    const float* W = blockIdx.z ? Wv : Wx;
    float* out     = blockIdx.z ? vout : out0;
    const int tid = threadIdx.x;
    const int m0 = blockIdx.x * 128;
    const int n0 = blockIdx.y * 128;
    const int tx = tid & 15, ty = tid >> 4;
    const int ar = tid >> 1, ak = (tid & 1) * 8;
    const int br = tid >> 4, bn = (tid & 15) * 8;
    float acc[8][8] = {};
    for (int k0 = 0; k0 < 512; k0 += 16) {
        if (k0) __syncthreads();
        float4 a0 = *(const float4*)&X[(size_t)(m0 + ar) * 512 + k0 + ak];
        float4 a1 = *(const float4*)&X[(size_t)(m0 + ar) * 512 + k0 + ak + 4];
        float4 b0 = *(const float4*)&W[(size_t)(k0 + br) * 1024 + n0 + bn];
        float4 b1 = *(const float4*)&W[(size_t)(k0 + br) * 1024 + n0 + bn + 4];
        As[ak + 0][ar] = a0.x; As[ak + 1][ar] = a0.y;
        As[ak + 2][ar] = a0.z; As[ak + 3][ar] = a0.w;
        As[ak + 4][ar] = a1.x; As[ak + 5][ar] = a1.y;
        As[ak + 6][ar] = a1.z; As[ak + 7][ar] = a1.w;
        *(float4*)&Bs[br][bn]     = b0;
        *(float4*)&Bs[br][bn + 4] = b1;
        __syncthreads();
        #pragma unroll
        for (int kk = 0; kk < 16; ++kk) {
            float4 xa = *(const float4*)&As[kk][ty * 8];
            float4 xb = *(const float4*)&As[kk][ty * 8 + 4];
            float4 ya = *(const float4*)&Bs[kk][tx * 8];
            float4 yb = *(const float4*)&Bs[kk][tx * 8 + 4];
            float a[8] = {xa.x, xa.y, xa.z, xa.w, xb.x, xb.y, xb.z, xb.w};
            float b[8] = {ya.x, ya.y, ya.z, ya.w, yb.x, yb.y, yb.z, yb.w};
            #pragma unroll
            for (int i = 0; i < 8; ++i)
                #pragma unroll
                for (int j = 0; j < 8; ++j)
                    acc[i][j] += a[i] * b[j];
        }
    }
    #pragma unroll
    for (int i = 0; i < 8; ++i) {
        float4 r0, r1;
        r0.x = acc[i][0]; r0.y = acc[i][1]; r0.z = acc[i][2]; r0.w = acc[i][3];
        r1.x = acc[i][4]; r1.y = acc[i][5]; r1.z = acc[i][6]; r1.w = acc[i][7];
        float* op = &out[(size_t)(m0 + ty * 8 + i) * 1024 + n0 + tx * 8];
        *(float4*)op       = r0;
        *(float4*)(op + 4) = r1;
    }
}

// ---------------------------------------------------------------------------
// q, k, lambda projections.
// ---------------------------------------------------------------------------
__global__ __launch_bounds__(256) void qkl_kernel(const float* __restrict__ X,
    const float* __restrict__ Wq, const float* __restrict__ Wk,
    const float* __restrict__ Wd, const float* __restrict__ bd,
    float* __restrict__ q, float* __restrict__ k, float* __restrict__ lam)
{
    __shared__ float xs[8 * 512];
    const int tid = threadIdx.x;
    const size_t row0 = (size_t)blockIdx.x * 8;
    #pragma unroll
    for (int c = 0; c < 4; ++c) {
        int f = (c * 256 + tid) * 4;
        *(float4*)&xs[f] = *(const float4*)&X[row0 * 512 + f];
    }
    __syncthreads();
    for (int t = tid; t < 264; t += 256) {
        int r = t / 33, c = t - r * 33;
        const float* xr = &xs[r * 512];
        const float* Wp; int ldw;
        if (c < 16)      { Wp = Wq + c;        ldw = 16; }
        else if (c < 32) { Wp = Wk + (c - 16); ldw = 16; }
        else             { Wp = Wd;            ldw = 1;  }
        float s = 0.f;
        for (int kk = 0; kk < 512; ++kk) s += xr[kk] * Wp[(size_t)kk * ldw];
        if (c < 16)      q[(row0 + r) * 16 + c] = s;
        else if (c < 32) k[(row0 + r) * 16 + (c - 16)] = s;
        else             lam[row0 + r] = 1.f / (1.f + expf(-(s + bd[0])));
    }
}

// ---------------------------------------------------------------------------
// Fused recurrence, R12: WAVE-AUTONOMOUS — no barriers, no LDS in the loop.
// 256 WGs x 512 threads (8 waves). Wave (bid, w) owns 8 cols of one batch
// over the FULL k=1024:   g=bid&7, s=bid>>3;  batch=2g+(w>>2),
// slice=s*4+(w&3), cols c0=slice*8 .. +7.
// Lane l: weights Wh[k=l*16..+15][c0..c0+7] in 128 VGPRs (static idx);
// polls its OWN 16 h-values (R8 protocol: +-4 self-signal, per-lane
// fast(sc0)/slow(sc0 sc1) scope from the XCC table, sticky escalation);
// matvec straight from the polled registers; 6-stage shfl_xor reduce;
// lane c (<8) holds the fast-weight scan for col c (F in regs, inputs
// prefetched one step ahead), adds pre, tanh, publishes sc0 sc1.
// ---------------------------------------------------------------------------
__global__ __launch_bounds__(512, 2) void rec_fused(
    const float* __restrict__ Wh, const float* __restrict__ qg,
    const float* __restrict__ kg, const float* __restrict__ vg,
    const float* __restrict__ lamg, const float* __restrict__ bias,
    float* __restrict__ out0, float* __restrict__ hfin,
    float* __restrict__ Ffin, float* __restrict__ hbuf,
    int* __restrict__ xcc_tab)
{
    const int tid = threadIdx.x;
    const int bid = blockIdx.x;
    const int g = bid & 7, s = bid >> 3;
    const int w = tid >> 6;
    const int lane = tid & 63;
    const int bg = g * 2 + (w >> 2);          // global batch
    const int c0 = (s * 4 + (w & 3)) * 8;     // col base (8 cols)

    // ---- publish my XCD id (value xcc+1; table memset to 0xFF each launch)
    const int my_xcc = __builtin_amdgcn_s_getreg(63508) & 0xF; // hwreg XCC_ID
    if (tid == 0) {
        int val = my_xcc + 1;
        int* tp = xcc_tab + bid;
        asm volatile("global_store_dword %0, %1, off sc0 sc1"
                     :: "v"(tp), "v"(val) : "memory");
    }

    // ---- weights: lane l covers k=l*16..+15, cols c0..+7; 128 regs, static
    float wr[128];
    #pragma unroll
    for (int i = 0; i < 16; ++i) {
        const float* wp = &Wh[(size_t)(lane * 16 + i) * 1024 + c0];
        float4 wa = *(const float4*)wp;
        float4 wb = *(const float4*)(wp + 4);
        wr[i * 8 + 0] = wa.x; wr[i * 8 + 1] = wa.y;
        wr[i * 8 + 2] = wa.z; wr[i * 8 + 3] = wa.w;
        wr[i * 8 + 4] = wb.x; wr[i * 8 + 5] = wb.y;
        wr[i * 8 + 6] = wb.z; wr[i * 8 + 7] = wb.w;
    }

    // ---- per-lane scope detect: producer WG of lane's k-window
    int fastf;
    {
        const int* tp = xcc_tab + ((lane >> 1) * 8 + g);
        int tv;
        for (;;) {
            asm volatile("global_load_dword %0, %1, off sc0 sc1\n\t"
                         "s_waitcnt vmcnt(0)"
                         : "=&v"(tv) : "v"(tp) : "memory");
            if (__all(tv != -1)) break;
            __builtin_amdgcn_s_sleep(1);
        }
        fastf = ((tv - 1) == my_xcc) ? 1 : 0;
    }

    // ---- scan state (lanes 0..7 active; col = c0 + lane)
    const bool isScan = (lane < 8);
    float F[16];
    #pragma unroll
    for (int r = 0; r < 16; ++r) F[r] = 0.f;
    float bias_r = 0.f, plam = 0.f, pv = 0.f, pxw = 0.f;
    float4 pq[4], pk4[4];
    #pragma unroll
    for (int r4 = 0; r4 < 4; ++r4) {
        pq[r4]  = make_float4(0.f, 0.f, 0.f, 0.f);
        pk4[r4] = make_float4(0.f, 0.f, 0.f, 0.f);
    }
    if (isScan) {
        bias_r = bias[c0 + lane];
        const size_t row = (size_t)bg * Tc;             // t = 0 inputs
        plam = lamg[row];
        pv   = vg[row * Hc + c0 + lane];
        pxw  = out0[row * Hc + c0 + lane];
        const float* qp  = qg + row * 16;
        const float* kpp = kg + row * 16;
        #pragma unroll
        for (int r4 = 0; r4 < 4; ++r4) {
            pq[r4]  = *(const float4*)(qp + r4 * 4);
            pk4[r4] = *(const float4*)(kpp + r4 * 4);
        }
    }

    for (int t = 0; t < Tc; ++t) {
        float* h_rd = hbuf + (t & 1) * (16 * 1024) + bg * 1024;
        float* h_wr = hbuf + ((t + 1) & 1) * (16 * 1024) + bg * 1024;
        const float off_r = ((t >> 1) & 1) ? 4.0f : 0.0f;
        const float off_w = (((t + 1) >> 1) & 1) ? 4.0f : 0.0f;

        // ---- scan step t (lanes<8) + prefetch t+1 (hides under poll) ----
        float pre_val = 0.f;
        if (isScan) {
            float rd = 0.f;
            #pragma unroll
            for (int r4 = 0; r4 < 4; ++r4) {
                float f0 = F[r4 * 4 + 0], f1 = F[r4 * 4 + 1];
                float f2 = F[r4 * 4 + 2], f3 = F[r4 * 4 + 3];
                f0 = plam * f0 + pv * pk4[r4].x; rd += f0 * pq[r4].x;
                f1 = plam * f1 + pv * pk4[r4].y; rd += f1 * pq[r4].y;
                f2 = plam * f2 + pv * pk4[r4].z; rd += f2 * pq[r4].z;
                f3 = plam * f3 + pv * pk4[r4].w; rd += f3 * pq[r4].w;
                F[r4 * 4 + 0] = f0; F[r4 * 4 + 1] = f1;
                F[r4 * 4 + 2] = f2; F[r4 * 4 + 3] = f3;
            }
            pre_val = pxw + rd + bias_r;
            if (t == Tc - 1) {
                #pragma unroll
                for (int r = 0; r < 16; ++r)
                    Ffin[((size_t)bg * Hc + c0 + lane) * 16 + r] = F[r];
            } else {
                const size_t row = (size_t)bg * Tc + (t + 1);
                plam = lamg[row];
                pv   = vg[row * Hc + c0 + lane];
                pxw  = out0[row * Hc + c0 + lane];
                const float* qp  = qg + row * 16;
                const float* kpp = kg + row * 16;
                #pragma unroll
                for (int r4 = 0; r4 < 4; ++r4) {
                    pq[r4]  = *(const float4*)(qp + r4 * 4);
                    pk4[r4] = *(const float4*)(kpp + r4 * 4);
                }
            }
        }

        // ---- poll own 16 h-values (k = lane*16..+15) ----
        float4 r0, r1, r2, r3;
        if (t > 0) {
            const float lo = off_r - 1.5f, hi = off_r + 1.5f;
            const float* p0 = h_rd + lane * 16;
            int tries = 0;
            for (;;) {
                if (fastf) {
                    asm volatile(
                        "global_load_dwordx4 %0, %4, off sc0\n\t"
                        "global_load_dwordx4 %1, %4, off offset:16 sc0\n\t"
                        "global_load_dwordx4 %2, %4, off offset:32 sc0\n\t"
                        "global_load_dwordx4 %3, %4, off offset:48 sc0\n\t"
                        "s_waitcnt vmcnt(0)"
                        : "=&v"(r0), "=&v"(r1), "=&v"(r2), "=&v"(r3)
                        : "v"(p0) : "memory");
                } else {
                    asm volatile(
                        "global_load_dwordx4 %0, %4, off sc0 sc1\n\t"
                        "global_load_dwordx4 %1, %4, off offset:16 sc0 sc1\n\t"
                        "global_load_dwordx4 %2, %4, off offset:32 sc0 sc1\n\t"
                        "global_load_dwordx4 %3, %4, off offset:48 sc0 sc1\n\t"
                        "s_waitcnt vmcnt(0)"
                        : "=&v"(r0), "=&v"(r1), "=&v"(r2), "=&v"(r3)
                        : "v"(p0) : "memory");
                }
                bool ok = r0.x > lo && r0.x < hi && r0.y > lo && r0.y < hi
                       && r0.z > lo && r0.z < hi && r0.w > lo && r0.w < hi
                       && r1.x > lo && r1.x < hi && r1.y > lo && r1.y < hi
                       && r1.z > lo && r1.z < hi && r1.w > lo && r1.w < hi
                       && r2.x > lo && r2.x < hi && r2.y > lo && r2.y < hi
                       && r2.z > lo && r2.z < hi && r2.w > lo && r2.w < hi
                       && r3.x > lo && r3.x < hi && r3.y > lo && r3.y < hi
                       && r3.z > lo && r3.z < hi && r3.w > lo && r3.w < hi;
                if (ok) break;
                if (fastf && ++tries > 64) fastf = 0;  // sticky escalation
            }
            r0.x -= off_r; r0.y -= off_r; r0.z -= off_r; r0.w -= off_r;
            r1.x -= off_r; r1.y -= off_r; r1.z -= off_r; r1.w -= off_r;
            r2.x -= off_r; r2.y -= off_r; r2.z -= off_r; r2.w -= off_r;
            r3.x -= off_r; r3.y -= off_r; r3.z -= off_r; r3.w -= off_r;
        } else {
            r0 = make_float4(0.f, 0.f, 0.f, 0.f);
            r1 = r0; r2 = r0; r3 = r0;
        }

        // ---- matvec from registers: 128 FMA ----
        float acc[8];
        #pragma unroll
        for (int c = 0; c < 8; ++c) acc[c] = 0.f;
        const float hv16[16] = {r0.x, r0.y, r0.z, r0.w, r1.x, r1.y, r1.z, r1.w,
                                r2.x, r2.y, r2.z, r2.w, r3.x, r3.y, r3.z, r3.w};
        #pragma unroll
        for (int i = 0; i < 16; ++i)
            #pragma unroll
            for (int c = 0; c < 8; ++c)
                acc[c] += hv16[i] * wr[i * 8 + c];

        // ---- full butterfly reduce over 64 lanes (6 stages x 8 cols) ----
        #pragma unroll
        for (int c = 0; c < 8; ++c) {
            float sum = acc[c];
            sum += __shfl_xor(sum, 1);
            sum += __shfl_xor(sum, 2);
            sum += __shfl_xor(sum, 4);
            sum += __shfl_xor(sum, 8);
            sum += __shfl_xor(sum, 16);
            sum += __shfl_xor(sum, 32);
            acc[c] = sum;
        }

        // ---- lane c: finish col c0+c, publish ----
        if (isScan) {
            float hvv = 0.f;
            #pragma unroll
            for (int c = 0; c < 8; ++c)
                if (lane == c) hvv = acc[c];
            float hv = tanhf(hvv + pre_val);
            float sv = hv + off_w;             // self-signaling store
            float* hp = h_wr + c0 + lane;
            asm volatile("global_store_dword %0, %1, off sc0 sc1"
                         :: "v"(hp), "v"(sv) : "memory");
            size_t oidx = ((size_t)bg * Tc + t) * Hc + c0 + lane;
            out0[oidx] = hv;
            if (t == Tc - 1) hfin[(size_t)bg * Hc + c0 + lane] = hv;
        }
    }
}

// ---------------------------------------------------------------------------
extern "C" void kernel_launch(void* const* d_in, const int* in_sizes, int n_in,
                              void* d_out, int out_size, void* d_ws, size_t ws_size,
                              hipStream_t stream)
{
    const float* x    = (const float*)d_in[0];
    const float* Wx   = (const float*)d_in[1];
    const float* Wh   = (const float*)d_in[2];
    const float* Wq   = (const float*)d_in[3];
    const float* Wk   = (const float*)d_in[4];
    const float* Wv   = (const float*)d_in[5];
    const float* Wd   = (const float*)d_in[6];
    const float* bias = (const float*)d_in[7];
    const float* bd   = (const float*)d_in[8];

    float* out0 = (float*)d_out;                    // (B,T,H): xw, then h
    float* hfin = out0 + (size_t)Bc * Tc * Hc;      // (B,H)
    float* Ffin = hfin + (size_t)Bc * Hc;           // (B,H,R)

    float* wsf  = (float*)d_ws;
    float* v    = wsf;                               // B*T*H
    float* q    = v + (size_t)Bc * Tc * Hc;          // B*T*R
    float* k    = q + (size_t)Bc * Tc * Rc;          // B*T*R
    float* lam  = k + (size_t)Bc * Tc * Rc;          // B*T
    float* hbuf = lam + (size_t)Bc * Tc;             // 2 * B*H ping-pong
    int*   xcc  = (int*)(hbuf + 2 * (size_t)Bc * Hc);// 256 entries

    // 0x7F7F7F7F == 3.39e38f: invalid under both offsets -> poll-safe init.
    hipMemsetAsync(hbuf, 0x7F, 2 * (size_t)Bc * Hc * sizeof(float), stream);
    hipMemsetAsync(xcc, 0xFF, 256 * sizeof(int), stream);

    dim3 gp(256, 8, 2);
    gemm_fused<<<gp, 256, 0, stream>>>(x, Wx, Wv, out0, v);
    qkl_kernel<<<4096, 256, 0, stream>>>(x, Wq, Wk, Wd, bd, q, k, lam);
    rec_fused<<<256, 512, 0, stream>>>(Wh, q, k, v, lam, bias,
                                       out0, hfin, Ffin, hbuf, xcc);
}

// Round 13
// 7455.425 us; speedup vs baseline: 1.5061x; 1.5061x over previous
//
#include <hip/hip_runtime.h>
#include <math.h>

#define Bc 16
#define Tc 2048
#define Dc 512
#define Hc 1024
#define Rc 16

// ---------------------------------------------------------------------------
// Merged projection kernel. One dispatch, grid (256, 8, 3):
//   z=0: xw = X@Wx   (BM=128, BN=128, 8x8 micro-tile)
//   z=1: v  = X@Wv   (same)
//   z=2: q/k/lambda  (block = 16 rows of x staged in LDS; 528 dots)
// The 2048 cheap z=2 blocks fill CU slots alongside the GEMM blocks, so
// the former 0.33 ms serial qkl dispatch rides free inside the GEMM time.
// ---------------------------------------------------------------------------
__global__ __launch_bounds__(256) void proj_fused(const float* __restrict__ X,
    const float* __restrict__ Wx, const float* __restrict__ Wv,
    const float* __restrict__ Wq, const float* __restrict__ Wk,
    const float* __restrict__ Wd, const float* __restrict__ bd,
    float* __restrict__ out0, float* __restrict__ vout,
    float* __restrict__ q, float* __restrict__ k, float* __restrict__ lam)
{
    __shared__ float smem[8192];   // 32 KB, shared by both paths
    const int tid = threadIdx.x;

    if (blockIdx.z < 2) {
        // ---------------- GEMM path ----------------
        float (*As)[128] = (float (*)[128])smem;          // [16][128]
        float (*Bs)[128] = (float (*)[128])(smem + 2048); // [16][128]
        const float* W = blockIdx.z ? Wv : Wx;
        float* out     = blockIdx.z ? vout : out0;
        const int m0 = blockIdx.x * 128;
        const int n0 = blockIdx.y * 128;
        const int tx = tid & 15, ty = tid >> 4;
        const int ar = tid >> 1, ak = (tid & 1) * 8;
        const int br = tid >> 4, bn = (tid & 15) * 8;
        float acc[8][8] = {};
        for (int k0 = 0; k0 < 512; k0 += 16) {
            if (k0) __syncthreads();
            float4 a0 = *(const float4*)&X[(size_t)(m0 + ar) * 512 + k0 + ak];
            float4 a1 = *(const float4*)&X[(size_t)(m0 + ar) * 512 + k0 + ak + 4];
            float4 b0 = *(const float4*)&W[(size_t)(k0 + br) * 1024 + n0 + bn];
            float4 b1 = *(const float4*)&W[(size_t)(k0 + br) * 1024 + n0 + bn + 4];
            As[ak + 0][ar] = a0.x; As[ak + 1][ar] = a0.y;
            As[ak + 2][ar] = a0.z; As[ak + 3][ar] = a0.w;
            As[ak + 4][ar] = a1.x; As[ak + 5][ar] = a1.y;
            As[ak + 6][ar] = a1.z; As[ak + 7][ar] = a1.w;
            *(float4*)&Bs[br][bn]     = b0;
            *(float4*)&Bs[br][bn + 4] = b1;
            __syncthreads();
            #pragma unroll
            for (int kk = 0; kk < 16; ++kk) {
                float4 xa = *(const float4*)&As[kk][ty * 8];
                float4 xb = *(const float4*)&As[kk][ty * 8 + 4];
                float4 ya = *(const float4*)&Bs[kk][tx * 8];
                float4 yb = *(const float4*)&Bs[kk][tx * 8 + 4];
                float a[8] = {xa.x, xa.y, xa.z, xa.w, xb.x, xb.y, xb.z, xb.w};
                float b[8] = {ya.x, ya.y, ya.z, ya.w, yb.x, yb.y, yb.z, yb.w};
                #pragma unroll
                for (int i = 0; i < 8; ++i)
                    #pragma unroll
                    for (int j = 0; j < 8; ++j)
                        acc[i][j] += a[i] * b[j];
            }
        }
        #pragma unroll
        for (int i = 0; i < 8; ++i) {
            float4 r0, r1;
            r0.x = acc[i][0]; r0.y = acc[i][1]; r0.z = acc[i][2]; r0.w = acc[i][3];
            r1.x = acc[i][4]; r1.y = acc[i][5]; r1.z = acc[i][6]; r1.w = acc[i][7];
            float* op = &out[(size_t)(m0 + ty * 8 + i) * 1024 + n0 + tx * 8];
            *(float4*)op       = r0;
            *(float4*)(op + 4) = r1;
        }
    } else {
        // ---------------- q/k/lambda path ----------------
        float* xs = smem;                                  // 16 rows x 512
        const int rb = blockIdx.x * 8 + blockIdx.y;        // 0..2047
        const size_t row0 = (size_t)rb * 16;
        #pragma unroll
        for (int c = 0; c < 8; ++c) {
            int f = (c * 256 + tid) * 4;
            *(float4*)&xs[f] = *(const float4*)&X[row0 * 512 + f];
        }
        __syncthreads();
        for (int t = tid; t < 528; t += 256) {
            int r = t / 33, c = t - r * 33;
            const float* xr = &xs[r * 512];
            const float* Wp; int ldw;
            if (c < 16)      { Wp = Wq + c;        ldw = 16; }
            else if (c < 32) { Wp = Wk + (c - 16); ldw = 16; }
            else             { Wp = Wd;            ldw = 1;  }
            float s = 0.f;
            for (int kk = 0; kk < 512; ++kk) s += xr[kk] * Wp[(size_t)kk * ldw];
            if (c < 16)      q[(row0 + r) * 16 + c] = s;
            else if (c < 32) k[(row0 + r) * 16 + (c - 16)] = s;
            else             lam[row0 + r] = 1.f / (1.f + expf(-(s + bd[0])));
        }
    }
}

// ---------------------------------------------------------------------------
// Fused recurrence — byte-identical to the R8/R11-proven kernel (6.5 ms):
// XCD-local exchange groups, per-thread fast/slow scope select with sticky
// escalation, wave3 fused fast-weight scan, 4-wave matvec + butterfly,
// wave0 finisher. DO NOT enlarge per-thread state (R10/R12: weight spill).
// ---------------------------------------------------------------------------
__global__ __launch_bounds__(256, 1) void rec_fused(
    const float* __restrict__ Wh, const float* __restrict__ qg,
    const float* __restrict__ kg, const float* __restrict__ vg,
    const float* __restrict__ lamg, const float* __restrict__ bias,
    float* __restrict__ out0, float* __restrict__ hfin,
    float* __restrict__ Ffin, float* __restrict__ hbuf,
    int* __restrict__ xcc_tab)
{
    __shared__ float hs[2 * 1152];     // phys(b,k) = b*1152 + (k>>5)*36 + (k&31)
    __shared__ float red2[2][256];     // [buf][wave*64 + cu*8 + z]
    __shared__ float pre_lds[2][64];   // [buf][bb*32 + ci]
    __shared__ float F_lds[64][17];    // fast-weight state, pad 17

    const int tid = threadIdx.x;
    const int bid = blockIdx.x;
    const int g = bid & 7, sl = bid >> 3;
    const int c0 = sl * 32;
    const int kp = tid >> 3;          // k-part: 32 k's (kp*32 .. +31)
    const int cu = tid & 7;           // col unit: 4 cols (c0 + cu*4 + j)
    const int wv = tid >> 6;

    // ---- publish my XCD id (value xcc+1; table memset to 0xFF each launch)
    const int my_xcc = __builtin_amdgcn_s_getreg(63508) & 0xF; // hwreg XCC_ID
    if (tid == 0) {
        int val = my_xcc + 1;
        int* tp = xcc_tab + bid;
        asm volatile("global_store_dword %0, %1, off sc0 sc1"
                     :: "v"(tp), "v"(val) : "memory");
    }

    // ---- weights: 128 regs/thread, all indices compile-time
    float wr[128];
    #pragma unroll
    for (int i = 0; i < 32; ++i) {
        float4 w4 = *(const float4*)&Wh[(size_t)(kp * 32 + i) * 1024 + c0 + cu * 4];
        wr[i * 4 + 0] = w4.x; wr[i * 4 + 1] = w4.y;
        wr[i * 4 + 2] = w4.z; wr[i * 4 + 3] = w4.w;
    }

    // ---- stage/poll geometry: thread owns 8 h values of one batch
    const int sb_ = tid >> 7;                // batch-in-group 0/1
    const int f   = (tid & 127) * 8;         // col offset 0..1016
    float* stage_base = &hs[sb_ * 1152 + (f >> 5) * 36 + (f & 31)];

    // ---- scope detect: producer of my window
    int fastf;
    {
        const int prod_bid = (f >> 5) * 8 + g;
        const int* tp = xcc_tab + prod_bid;
        int tv;
        for (;;) {
            asm volatile("global_load_dword %0, %1, off sc0 sc1\n\t"
                         "s_waitcnt vmcnt(0)"
                         : "=&v"(tv) : "v"(tp) : "memory");
            if (tv != -1) break;
        }
        fastf = ((tv - 1) == my_xcc) ? 1 : 0;
    }

    // ---- roles
    const int j64 = tid & 63;
    const int fb = j64 >> 5, fci = j64 & 31;   // (batch-in-group, col-in-slice)
    const int bg = g * 2 + fb;                 // global batch
    const bool isScan = (tid >= 192);
    const bool isFin  = (tid < 64);

    float bias_r = 0.f, plam = 0.f, pv = 0.f, pxw = 0.f;
    float4 pq[4], pk4[4];
    if (isScan) {
        bias_r = bias[c0 + fci];
        #pragma unroll
        for (int r = 0; r < 16; ++r) F_lds[j64][r] = 0.f;
        const size_t row = (size_t)bg * Tc;             // t = 0 inputs
        plam = lamg[row];
        pv   = vg[row * Hc + c0 + fci];
        pxw  = out0[row * Hc + c0 + fci];
        const float* qp  = qg + row * 16;
        const float* kpp = kg + row * 16;
        #pragma unroll
        for (int r4 = 0; r4 < 4; ++r4) {
            pq[r4]  = *(const float4*)(qp + r4 * 4);
            pk4[r4] = *(const float4*)(kpp + r4 * 4);
        }
    }

    for (int t = 0; t < Tc; ++t) {
        const int buf = t & 1;
        float* h_rd = hbuf + (t & 1) * (16 * 1024) + g * 2048;
        float* h_wr = hbuf + ((t + 1) & 1) * (16 * 1024) + g * 2048;
        const float off_r = ((t >> 1) & 1) ? 4.0f : 0.0f;
        const float off_w = (((t + 1) >> 1) & 1) ? 4.0f : 0.0f;

        // ---- wave3: fast-weight scan (hidden under the poll) ----
        if (isScan) {
            float rd = 0.f;
            #pragma unroll
            for (int r4 = 0; r4 < 4; ++r4) {
                float f0 = F_lds[j64][r4 * 4 + 0];
                float f1 = F_lds[j64][r4 * 4 + 1];
                float f2 = F_lds[j64][r4 * 4 + 2];
                float f3 = F_lds[j64][r4 * 4 + 3];
                f0 = plam * f0 + pv * pk4[r4].x; rd += f0 * pq[r4].x;
                f1 = plam * f1 + pv * pk4[r4].y; rd += f1 * pq[r4].y;
                f2 = plam * f2 + pv * pk4[r4].z; rd += f2 * pq[r4].z;
                f3 = plam * f3 + pv * pk4[r4].w; rd += f3 * pq[r4].w;
                F_lds[j64][r4 * 4 + 0] = f0;
                F_lds[j64][r4 * 4 + 1] = f1;
                F_lds[j64][r4 * 4 + 2] = f2;
                F_lds[j64][r4 * 4 + 3] = f3;
            }
            pre_lds[buf][j64] = pxw + rd + bias_r;
            if (t == Tc - 1) {
                #pragma unroll
                for (int r = 0; r < 16; ++r)
                    Ffin[((size_t)bg * Hc + c0 + fci) * 16 + r] = F_lds[j64][r];
            } else {
                const size_t row = (size_t)bg * Tc + (t + 1);
                plam = lamg[row];
                pv   = vg[row * Hc + c0 + fci];
                pxw  = out0[row * Hc + c0 + fci];
                const float* qp  = qg + row * 16;
                const float* kpp = kg + row * 16;
                #pragma unroll
                for (int r4 = 0; r4 < 4; ++r4) {
                    pq[r4]  = *(const float4*)(qp + r4 * 4);
                    pk4[r4] = *(const float4*)(kpp + r4 * 4);
                }
            }
        }

        // ---- poll own 8-value window, stage into hs ----
        if (t > 0) {
            const float lo = off_r - 1.5f, hi = off_r + 1.5f;
            const float* p0 = h_rd + sb_ * 1024 + f;
            const float* p1 = p0 + 4;
            float4 r0, r1;
            int tries = 0;
            for (;;) {
                if (fastf) {
                    asm volatile(
                        "global_load_dwordx4 %0, %2, off sc0\n\t"
                        "global_load_dwordx4 %1, %3, off sc0\n\t"
                        "s_waitcnt vmcnt(0)"
                        : "=&v"(r0), "=&v"(r1)
                        : "v"(p0), "v"(p1) : "memory");
                } else {
                    asm volatile(
                        "global_load_dwordx4 %0, %2, off sc0 sc1\n\t"
                        "global_load_dwordx4 %1, %3, off sc0 sc1\n\t"
                        "s_waitcnt vmcnt(0)"
                        : "=&v"(r0), "=&v"(r1)
                        : "v"(p0), "v"(p1) : "memory");
                }
                bool ok = r0.x > lo && r0.x < hi && r0.y > lo && r0.y < hi
                       && r0.z > lo && r0.z < hi && r0.w > lo && r0.w < hi
                       && r1.x > lo && r1.x < hi && r1.y > lo && r1.y < hi
                       && r1.z > lo && r1.z < hi && r1.w > lo && r1.w < hi;
                if (ok) break;
                if (fastf && ++tries > 64) fastf = 0;  // sticky escalation
            }
            r0.x -= off_r; r0.y -= off_r; r0.z -= off_r; r0.w -= off_r;
            r1.x -= off_r; r1.y -= off_r; r1.z -= off_r; r1.w -= off_r;
            *(float4*)(stage_base)     = r0;
            *(float4*)(stage_base + 4) = r1;
        } else {
            float4 z = {0.f, 0.f, 0.f, 0.f};
            *(float4*)(stage_base)     = z;
            *(float4*)(stage_base + 4) = z;
        }
        __syncthreads();                       // B: hs ready

        // ---- matvec: 16 b128 LDS reads, 256 FMAs per thread ----
        float acc[8];
        #pragma unroll
        for (int z = 0; z < 8; ++z) acc[z] = 0.f;
        #pragma unroll
        for (int bb = 0; bb < 2; ++bb) {
            const float* hb = &hs[bb * 1152 + kp * 36];
            #pragma unroll
            for (int i = 0; i < 8; ++i) {
                float4 h4 = *(const float4*)(hb + i * 4);
                #pragma unroll
                for (int j = 0; j < 4; ++j)
                    acc[j * 2 + bb] += h4.x * wr[(i * 4 + 0) * 4 + j]
                                     + h4.y * wr[(i * 4 + 1) * 4 + j]
                                     + h4.z * wr[(i * 4 + 2) * 4 + j]
                                     + h4.w * wr[(i * 4 + 3) * 4 + j];
            }
        }

        // ---- butterfly over the wave's 8 k-parts (lane bits 3,4,5) ----
        #pragma unroll
        for (int z = 0; z < 8; ++z) {
            float s = acc[z];
            s += __shfl_xor(s, 8);
            s += __shfl_xor(s, 16);
            s += __shfl_xor(s, 32);
            acc[z] = s;
        }
        if (j64 < 8) {                          // one lane per cu
            float4 ra, rb;
            ra.x = acc[0]; ra.y = acc[1]; ra.z = acc[2]; ra.w = acc[3];
            rb.x = acc[4]; rb.y = acc[5]; rb.z = acc[6]; rb.w = acc[7];
            *(float4*)&red2[buf][wv * 64 + j64 * 8]     = ra;
            *(float4*)&red2[buf][wv * 64 + j64 * 8 + 4] = rb;
        }
        __syncthreads();                       // C: red2 + pre_lds ready

        // ---- finisher: combine 4 wave-partials, tanh, store ----
        if (isFin) {
            const int cu_f = fci >> 2, jf = fci & 3;
            const int z = jf * 2 + fb;
            float tot = pre_lds[buf][j64];
            #pragma unroll
            for (int ww = 0; ww < 4; ++ww)
                tot += red2[buf][ww * 64 + cu_f * 8 + z];
            float hv = tanhf(tot);
            float sv = hv + off_w;             // self-signaling store first
            float* hp = h_wr + fb * 1024 + c0 + fci;
            asm volatile(
                "global_store_dword %0, %1, off sc0 sc1"
                :: "v"(hp), "v"(sv) : "memory");
            size_t oidx = ((size_t)bg * Tc + t) * Hc + c0 + fci;
            out0[oidx] = hv;
            if (t == Tc - 1) hfin[(size_t)bg * Hc + c0 + fci] = hv;
        }
    }
}

// ---------------------------------------------------------------------------
extern "C" void kernel_launch(void* const* d_in, const int* in_sizes, int n_in,
                              void* d_out, int out_size, void* d_ws, size_t ws_size,
                              hipStream_t stream)
{
    const float* x    = (const float*)d_in[0];
    const float* Wx   = (const float*)d_in[1];
    const float* Wh   = (const float*)d_in[2];
    const float* Wq   = (const float*)d_in[3];
    const float* Wk   = (const float*)d_in[4];
    const float* Wv   = (const float*)d_in[5];
    const float* Wd   = (const float*)d_in[6];
    const float* bias = (const float*)d_in[7];
    const float* bd   = (const float*)d_in[8];

    float* out0 = (float*)d_out;                    // (B,T,H): xw, then h
    float* hfin = out0 + (size_t)Bc * Tc * Hc;      // (B,H)
    float* Ffin = hfin + (size_t)Bc * Hc;           // (B,H,R)

    float* wsf  = (float*)d_ws;
    float* v    = wsf;                               // B*T*H
    float* q    = v + (size_t)Bc * Tc * Hc;          // B*T*R
    float* k    = q + (size_t)Bc * Tc * Rc;          // B*T*R
    float* lam  = k + (size_t)Bc * Tc * Rc;          // B*T
    float* hbuf = lam + (size_t)Bc * Tc;             // 2 * B*H ping-pong
    int*   xcc  = (int*)(hbuf + 2 * (size_t)Bc * Hc);// 256 entries

    // 0x7F7F7F7F == 3.39e38f: invalid under both offsets -> poll-safe init.
    hipMemsetAsync(hbuf, 0x7F, 2 * (size_t)Bc * Hc * sizeof(float), stream);
    hipMemsetAsync(xcc, 0xFF, 256 * sizeof(int), stream);

    dim3 gp(256, 8, 3);
    proj_fused<<<gp, 256, 0, stream>>>(x, Wx, Wv, Wq, Wk, Wd, bd,
                                       out0, v, q, k, lam);
    rec_fused<<<256, 256, 0, stream>>>(Wh, q, k, v, lam, bias,
                                       out0, hfin, Ffin, hbuf, xcc);
}